// Round 9
// baseline (350.677 us; speedup 1.0000x reference)
//
#include <hip/hip_runtime.h>
#include <hip/hip_bf16.h>

typedef __attribute__((ext_vector_type(4))) float f32x4;
typedef __attribute__((ext_vector_type(16))) float f32x16;
typedef __attribute__((ext_vector_type(8))) short short8;
typedef __attribute__((ext_vector_type(4))) unsigned int u32x4;
typedef __attribute__((ext_vector_type(2))) unsigned int u32x2;
typedef unsigned short u16;

__device__ __forceinline__ u16 f2bf(float x) {
  unsigned u = __float_as_uint(x);
  u += 0x7fffu + ((u >> 16) & 1u);   // RNE
  return (u16)(u >> 16);
}

__device__ __forceinline__ void gload_lds16(const void* g, void* l) {
  __builtin_amdgcn_global_load_lds(
      (__attribute__((address_space(1))) void*)g,
      (__attribute__((address_space(3))) void*)l, 16, 0, 0);
}

// -------------------- fp32 -> bf16 convert (all 3 inputs, one kernel) -------------
__global__ void cvt_all(const float* __restrict__ x, const float* __restrict__ wq,
                        const float* __restrict__ wp, ushort4* __restrict__ dst) {
  const int N1 = 1048576, N2 = 786432, NT = 2097152;
  for (int i = blockIdx.x * 256 + threadIdx.x; i < NT; i += 524288) {
    float4 v;
    if (i < N1)            v = ((const float4*)x)[i];
    else if (i < N1 + N2)  v = ((const float4*)wq)[i - N1];
    else                   v = ((const float4*)wp)[i - N1 - N2];
    ushort4 o;
    o.x = f2bf(v.x); o.y = f2bf(v.y); o.z = f2bf(v.z); o.w = f2bf(v.w);
    dst[i] = o;
  }
}

// ==================== 256x192 GEMM (QKV): C = A B^T + bias, bf16 out ==============
// (unchanged from R8 — see its header comment)
__global__ __launch_bounds__(512, 2) void gemm256_bt(
    const u16* __restrict__ A, const u16* __restrict__ B,
    const float* __restrict__ bias, u16* __restrict__ Cout,
    int M, int N, int K)
{
  __shared__ u16 LA[2][2][8192];
  __shared__ u16 LB[2][12288];

  const int tid  = threadIdx.x;
  const int w    = tid >> 6;
  const int lane = tid & 63;
  const int wm   = w >> 2;
  const int wn   = w & 3;
  const int hi   = lane >> 4;
  const int lo   = lane & 15;

  const int L  = (int)(blockIdx.x & 7) * 32 + (int)(blockIdx.x >> 3);
  const int bx = L >> 4, by = L & 15;
  const long brow = (long)by * 256;
  const long bcol = (long)bx * 192;

  f32x4 acc[8][3];
#pragma unroll
  for (int m = 0; m < 8; ++m)
#pragma unroll
    for (int n = 0; n < 3; ++n)
#pragma unroll
      for (int r = 0; r < 4; ++r) acc[m][n][r] = 0.0f;

  const int srow = lane >> 3;
  const int sg   = (lane & 7) ^ srow;
  const int l7   = lo & 7;

  auto stA = [&](int kt, int bi, int i) {
    const long k0 = (long)kt * 64;
#pragma unroll
    for (int mh = 0; mh < 2; ++mh) {
      const long r = brow + mh * 128 + i * 64 + w * 8 + srow;
      gload_lds16(A + r * K + k0 + sg * 8, &LA[bi][mh][i * 4096 + w * 512]);
    }
  };
  auto stB = [&](int kt, int bi, int u) {
    const long k0 = (long)kt * 64;
    const long r = bcol + u * 64 + w * 8 + srow;
    gload_lds16(B + r * K + k0 + sg * 8, &LB[bi][u * 4096 + w * 512]);
  };

  short8 a[4][2], b[3][2];
  auto rdA = [&](int bi, int mq) {
#pragma unroll
    for (int f = 0; f < 4; ++f) {
      const int rl = mq * 64 + f * 16 + lo;
#pragma unroll
      for (int ks = 0; ks < 2; ++ks)
        a[f][ks] = *(const short8*)(&LA[bi][wm][rl * 64 + ((ks * 4 + hi) ^ l7) * 8]);
    }
  };
  auto rdB = [&](int bi) {
#pragma unroll
    for (int f = 0; f < 3; ++f) {
      const int rl = wn * 48 + f * 16 + lo;
#pragma unroll
      for (int ks = 0; ks < 2; ++ks)
        b[f][ks] = *(const short8*)(&LB[bi][rl * 64 + ((ks * 4 + hi) ^ l7) * 8]);
    }
  };

#define MFMA24(mq)                                                                  \
  __builtin_amdgcn_s_setprio(1);                                                    \
  _Pragma("unroll")                                                                 \
  for (int f = 0; f < 4; ++f)                                                       \
    _Pragma("unroll")                                                               \
    for (int n = 0; n < 3; ++n)                                                     \
      _Pragma("unroll")                                                             \
      for (int ks = 0; ks < 2; ++ks)                                                \
        acc[(mq)*4 + f][n] = __builtin_amdgcn_mfma_f32_16x16x32_bf16(               \
            a[f][ks], b[n][ks], acc[(mq)*4 + f][n], 0, 0, 0);                       \
  __builtin_amdgcn_s_setprio(0);

#define PHASE_WAIT()                                      \
  __builtin_amdgcn_s_barrier();                           \
  asm volatile("s_waitcnt lgkmcnt(0)" ::: "memory");      \
  __builtin_amdgcn_sched_barrier(0);

  const int nkt = K >> 6;
  stA(0, 0, 0); stA(0, 0, 1); stB(0, 0, 0); stB(0, 0, 1); stB(0, 0, 2);
  stA(1, 1, 0); stA(1, 1, 1); stB(1, 1, 0); stB(1, 1, 1); stB(1, 1, 2);
  asm volatile("s_waitcnt vmcnt(7)" ::: "memory");
  __builtin_amdgcn_s_barrier();

  for (int it = 0; it < (nkt >> 1); ++it) {
    const int t2 = 2 * it + 2, t3 = 2 * it + 3;
    rdA(0, 0); rdB(0);
    if (it > 0) stA(2 * it + 1, 1, 1);
    PHASE_WAIT(); MFMA24(0); __builtin_amdgcn_s_barrier();
    rdA(0, 1);
    if (t2 < nkt) { stB(t2, 0, 0); stB(t2, 0, 1); stB(t2, 0, 2); stA(t2, 0, 0); }
    PHASE_WAIT(); MFMA24(1);
    if (t2 < nkt) { asm volatile("s_waitcnt vmcnt(5)" ::: "memory"); }
    else          { asm volatile("s_waitcnt vmcnt(0)" ::: "memory"); }
    __builtin_amdgcn_sched_barrier(0);
    __builtin_amdgcn_s_barrier();
    rdA(1, 0); rdB(1);
    if (t2 < nkt) stA(t2, 0, 1);
    PHASE_WAIT(); MFMA24(0); __builtin_amdgcn_s_barrier();
    rdA(1, 1);
    if (t3 < nkt) { stB(t3, 1, 0); stB(t3, 1, 1); stB(t3, 1, 2); stA(t3, 1, 0); }
    PHASE_WAIT(); MFMA24(1);
    if (t3 < nkt) { asm volatile("s_waitcnt vmcnt(5)" ::: "memory"); }
    __builtin_amdgcn_sched_barrier(0);
    __builtin_amdgcn_s_barrier();
  }
#undef MFMA24
#undef PHASE_WAIT

  const float SCC = 0.18033688011112042f;
  float bv[3];
#pragma unroll
  for (int n = 0; n < 3; ++n) bv[n] = bias[bcol + wn * 48 + n * 16 + lo];
#pragma unroll
  for (int m = 0; m < 8; ++m)
#pragma unroll
    for (int n = 0; n < 3; ++n) {
      const long colf = bcol + wn * 48 + n * 16;
      const float qsc = (colf < 1024) ? SCC : 1.0f;
#pragma unroll
      for (int r = 0; r < 4; ++r) {
        const long row = brow + wm * 128 + m * 16 + hi * 4 + r;
        Cout[row * (long)N + colf + lo] = f2bf((acc[m][n][r] + bv[n]) * qsc);
      }
    }
}

// -------------------- GEMM: C[M,N] = A[M,K] * B[N,K]^T + bias (128^2, 2-phase) ----
template<int OUT_BF16>
__global__ __launch_bounds__(256) void gemm_bt(
    const u16* __restrict__ A, const u16* __restrict__ B,
    const float* __restrict__ bias, void* __restrict__ Cout,
    int M, int N, int K)
{
  __shared__ u16 As[2][128 * 64];
  __shared__ u16 Bs[2][128 * 64];
  const int tid  = threadIdx.x;
  const int lane = tid & 63;
  const int w    = tid >> 6;
  const int wm   = w >> 1, wn = w & 1;
  const int hi   = lane >> 4;
  const int lo   = lane & 15;
  const int l7   = lo & 7;
  const long brow = (long)blockIdx.y * 128;
  const long bcol = (long)blockIdx.x * 128;

  f32x4 acc[4][4];
#pragma unroll
  for (int i = 0; i < 4; i++)
#pragma unroll
    for (int j = 0; j < 4; j++)
#pragma unroll
      for (int r = 0; r < 4; r++) acc[i][j][r] = 0.0f;

  const int srow = lane >> 3;
  const int sg   = (lane & 7) ^ srow;

  float bv[4];
#pragma unroll
  for (int fn = 0; fn < 4; fn++) bv[fn] = bias[bcol + wn * 64 + fn * 16 + lo];

  auto stage = [&](int kt, int bi) {
    const int k0 = kt << 6;
#pragma unroll
    for (int c = 0; c < 4; ++c) {
      const int chunk = (c << 2) + w;
      const int ra = (chunk << 3) + srow;
      gload_lds16(A + (size_t)(brow + ra) * K + k0 + sg * 8, &As[bi][chunk * 512]);
      gload_lds16(B + (size_t)(bcol + ra) * K + k0 + sg * 8, &Bs[bi][chunk * 512]);
    }
  };

  const int nkt = K >> 6;
  stage(0, 0);
  __syncthreads();
  int cur = 0;

  for (int kt = 0; kt < nkt; ++kt) {
    if (kt + 1 < nkt) stage(kt + 1, cur ^ 1);
#pragma unroll
    for (int ks = 0; ks < 2; ++ks) {
      short8 af[4], bfr[4];
      const int g = ((ks * 4 + hi) ^ l7) * 8;
#pragma unroll
      for (int f = 0; f < 4; f++) {
        af[f]  = *(const short8*)(&As[cur][(wm * 64 + f * 16 + lo) * 64 + g]);
        bfr[f] = *(const short8*)(&Bs[cur][(wn * 64 + f * 16 + lo) * 64 + g]);
      }
#pragma unroll
      for (int fm = 0; fm < 4; fm++)
#pragma unroll
        for (int fn = 0; fn < 4; fn++)
          acc[fm][fn] = __builtin_amdgcn_mfma_f32_16x16x32_bf16(af[fm], bfr[fn], acc[fm][fn], 0, 0, 0);
    }
    __syncthreads();
    cur ^= 1;
  }

#pragma unroll
  for (int fm = 0; fm < 4; fm++)
#pragma unroll
    for (int fn = 0; fn < 4; fn++)
#pragma unroll
      for (int r = 0; r < 4; r++) {
        const long row = brow + wm * 64 + fm * 16 + hi * 4 + r;
        const long col = bcol + wn * 64 + fn * 16 + lo;
        const float v = acc[fm][fn][r] + bv[fn];
        if (OUT_BF16) ((u16*)Cout)[row * (long)N + col] = f2bf(v);
        else          ((float*)Cout)[row * (long)N + col] = v;
      }
}

// -------------------- fused flash attention ----------------------------------------
// 12 warps = 4 q-subgroups (32 rows) x 3 KV-thirds (704/704/640 keys).
// Shift-free softmax (Q pre-scaled at GEMM epilogue) -> partials additive.
// LDS 72 KB: K dbuf 3x2x8KB + V single-buf 3x8KB -> 2 blocks/CU = 24 waves/CU.
// Per tile: {stK(t+1) | QK(t) | softmax | vmcnt(2)+bar | PV(t) | vmcnt(0)+bar | stV(t+1)}
// Ragged thirds: uniform 11-iteration loop, warp-uniform `act` predication,
// barriers unconditional.
__global__ __launch_bounds__(768, 6) void attn_fused(
    const u16* __restrict__ qkv, u16* __restrict__ out)
{
  __shared__ __align__(16) char smem[73728];

  const int tid  = threadIdx.x;
  const int w    = tid >> 6;         // 0..11
  const int lane = tid & 63;
  const int l31  = lane & 31;
  const int hc   = lane >> 5;        // wave half
  const int g1   = (lane >> 4) & 1;  // d16 select for tr-read
  const int l15  = lane & 15;
  const int third = w >> 2;          // KV third (0..2)
  const int qg   = w & 3;            // q subgroup (32 rows)

  const int bid  = blockIdx.x;
  const int xcd  = bid & 7;
  const int slot = bid >> 3;
  const int qb   = slot & 15;
  const int bh   = ((slot >> 4) << 3) | xcd;
  const int b    = bh >> 4, h = bh & 15;

  const int ntiles = (third < 2) ? 11 : 10;   // 32 tiles of 64 keys total
  const int st     = third * 11;              // 0, 11, 22

  short8 qf[4];
  {
    const u16* qp = qkv + (size_t)(b * 2048 + qb * 128 + qg * 32 + l31) * 3072 + h * 64 + hc * 8;
#pragma unroll
    for (int ds = 0; ds < 4; ++ds) qf[ds] = *(const short8*)(qp + ds * 16);
  }

  f32x16 acc0, acc1;
#pragma unroll
  for (int r = 0; r < 16; ++r) { acc0[r] = 0.f; acc1[r] = 0.f; }
  float lsum = 0.f;

  const int srow8 = lane >> 3;
  const int kgl   = (lane & 7) ^ srow8;
  const int vkey  = (lane >> 5) * 4 + ((lane >> 1) & 3);
  const int vd    = ((lane >> 3) & 3) * 16 + (lane & 1) * 8;

  auto kbuf = [&](int bi) { return (u16*)(smem + (size_t)(third * 2 + bi) * 8192); };
  u16* vb = (u16*)(smem + 49152 + (size_t)third * 8192);

  auto stK = [&](int t, int bi) {
    const size_t rbase = (size_t)(b * 2048 + t * 64);
    u16* Kb = kbuf(bi);
#pragma unroll
    for (int c = 0; c < 2; ++c) {
      const int chunk = qg * 2 + c;
      gload_lds16(qkv + (rbase + chunk * 8 + srow8) * 3072 + 1024 + h * 64 + kgl * 8,
                  Kb + chunk * 512);
    }
  };
  auto stV = [&](int t) {
    const size_t rbase = (size_t)(b * 2048 + t * 64);
#pragma unroll
    for (int c = 0; c < 2; ++c) {
      const int chunk = qg * 2 + c;
      gload_lds16(qkv + (rbase + chunk * 8 + vkey) * 3072 + 2048 + h * 64 + vd,
                  vb + chunk * 512);
    }
  };

  // prologue: K(st) -> kb0, V(st) -> vb; full drain + barrier
  stK(st, 0); stV(st);
  asm volatile("s_waitcnt vmcnt(0)" ::: "memory");
  __builtin_amdgcn_s_barrier();
  int cur = 0;

  for (int tt = 0; tt < 11; ++tt) {
    const bool act = tt < ntiles;
    const bool pfK = (tt + 1) < ntiles;    // uniform per warp
    const int  t   = st + tt;

    if (pfK) stK(t + 1, cur ^ 1);

    f32x16 s0, s1;
#pragma unroll
    for (int r = 0; r < 16; ++r) { s0[r] = 0.f; s1[r] = 0.f; }
    short8 pa[4];

    if (act) {
      const u16* Kc = kbuf(cur);
      __builtin_amdgcn_s_setprio(1);
#pragma unroll
      for (int ds = 0; ds < 4; ++ds) {
        const int gb = (((2 * ds + hc) ^ (lane & 7)) << 4);
        const short8 k0 = *(const short8*)((const char*)Kc + l31 * 128 + gb);
        const short8 k1 = *(const short8*)((const char*)Kc + 4096 + l31 * 128 + gb);
        s0 = __builtin_amdgcn_mfma_f32_32x32x16_bf16(k0, qf[ds], s0, 0, 0, 0);
        s1 = __builtin_amdgcn_mfma_f32_32x32x16_bf16(k1, qf[ds], s1, 0, 0, 0);
      }
      __builtin_amdgcn_s_setprio(0);

      // P = exp2(S) (Q pre-scaled; shift-free), accumulate row-sum
      float p[32];
#pragma unroll
      for (int r = 0; r < 16; ++r) {
        p[r]      = __builtin_amdgcn_exp2f(s0[r]);
        p[16 + r] = __builtin_amdgcn_exp2f(s1[r]);
      }
      {
        float a0 = 0.f, a1 = 0.f, a2 = 0.f, a3 = 0.f;
#pragma unroll
        for (int r = 0; r < 8; ++r) {
          a0 += p[r]; a1 += p[8 + r]; a2 += p[16 + r]; a3 += p[24 + r];
        }
        lsum += (a0 + a1) + (a2 + a3);
      }

      // PA-frags: cvt_pk pairs + permlane32_swap
#pragma unroll
      for (int ks = 0; ks < 4; ++ks) {
        const int bs = ks * 8;
        unsigned X0, X1, X2, X3;
        asm("v_cvt_pk_bf16_f32 %0, %1, %2" : "=v"(X0) : "v"(p[bs + 0]), "v"(p[bs + 1]));
        asm("v_cvt_pk_bf16_f32 %0, %1, %2" : "=v"(X1) : "v"(p[bs + 2]), "v"(p[bs + 3]));
        asm("v_cvt_pk_bf16_f32 %0, %1, %2" : "=v"(X2) : "v"(p[bs + 4]), "v"(p[bs + 5]));
        asm("v_cvt_pk_bf16_f32 %0, %1, %2" : "=v"(X3) : "v"(p[bs + 6]), "v"(p[bs + 7]));
        asm("v_permlane32_swap_b32 %0, %1" : "+v"(X0), "+v"(X2));
        asm("v_permlane32_swap_b32 %0, %1" : "+v"(X1), "+v"(X3));
        u32x4 wv;
        wv[0] = X0; wv[1] = X1; wv[2] = X2; wv[3] = X3;
        pa[ks] = __builtin_bit_cast(short8, wv);
      }
    }

    // mid gate: V(t) LDS-writes drained (this wave), K(t+1) may stay in flight
    if (pfK) { asm volatile("s_waitcnt vmcnt(2)" ::: "memory"); }
    else     { asm volatile("s_waitcnt vmcnt(0)" ::: "memory"); }
    __builtin_amdgcn_sched_barrier(0);
    __builtin_amdgcn_s_barrier();      // cross-warp: everyone's V writes visible

    if (act) {
      const unsigned va =
          (unsigned)(unsigned long long)(const __attribute__((address_space(3))) u16*)vb;
#pragma unroll
      for (int dt = 0; dt < 2; ++dt) {
        const unsigned vba = va + (unsigned)(hc * 1024 + dt * 256 + g1 * 128 + l15 * 8);
        u32x2 q0, q1, q2, q3, q4, q5, q6, q7;
        asm volatile("ds_read_b64_tr_b16 %0, %1"             : "=v"(q0) : "v"(vba));
        asm volatile("ds_read_b64_tr_b16 %0, %1 offset:512"  : "=v"(q1) : "v"(vba));
        asm volatile("ds_read_b64_tr_b16 %0, %1 offset:2048" : "=v"(q2) : "v"(vba));
        asm volatile("ds_read_b64_tr_b16 %0, %1 offset:2560" : "=v"(q3) : "v"(vba));
        asm volatile("ds_read_b64_tr_b16 %0, %1 offset:4096" : "=v"(q4) : "v"(vba));
        asm volatile("ds_read_b64_tr_b16 %0, %1 offset:4608" : "=v"(q5) : "v"(vba));
        asm volatile("ds_read_b64_tr_b16 %0, %1 offset:6144" : "=v"(q6) : "v"(vba));
        asm volatile("ds_read_b64_tr_b16 %0, %1 offset:6656" : "=v"(q7) : "v"(vba));
        asm volatile("s_waitcnt lgkmcnt(0)" ::: "memory");
        __builtin_amdgcn_sched_barrier(0);
        __builtin_amdgcn_s_setprio(1);
        f32x16 A = dt ? acc1 : acc0;
        {
          u32x4 bb; bb[0] = q0[0]; bb[1] = q0[1]; bb[2] = q1[0]; bb[3] = q1[1];
          A = __builtin_amdgcn_mfma_f32_32x32x16_bf16(pa[0], __builtin_bit_cast(short8, bb), A, 0, 0, 0);
        }
        {
          u32x4 bb; bb[0] = q2[0]; bb[1] = q2[1]; bb[2] = q3[0]; bb[3] = q3[1];
          A = __builtin_amdgcn_mfma_f32_32x32x16_bf16(pa[1], __builtin_bit_cast(short8, bb), A, 0, 0, 0);
        }
        {
          u32x4 bb; bb[0] = q4[0]; bb[1] = q4[1]; bb[2] = q5[0]; bb[3] = q5[1];
          A = __builtin_amdgcn_mfma_f32_32x32x16_bf16(pa[2], __builtin_bit_cast(short8, bb), A, 0, 0, 0);
        }
        {
          u32x4 bb; bb[0] = q6[0]; bb[1] = q6[1]; bb[2] = q7[0]; bb[3] = q7[1];
          A = __builtin_amdgcn_mfma_f32_32x32x16_bf16(pa[3], __builtin_bit_cast(short8, bb), A, 0, 0, 0);
        }
        __builtin_amdgcn_s_setprio(0);
        if (dt) acc1 = A; else acc0 = A;
      }
    }

    // end gate: K(t+1) drained (full tile of cover); then V(t+1) may overwrite vb
    asm volatile("s_waitcnt vmcnt(0)" ::: "memory");
    __builtin_amdgcn_sched_barrier(0);
    __builtin_amdgcn_s_barrier();

    if (pfK) stV(t + 1);
    cur ^= 1;
  }

  // ---- merge the 3 KV-third partials via LDS (shift-free => purely additive) ----
  float ltot = lsum + __shfl_xor(lsum, 32);
  float* MG = (float*)smem;
  if (third > 0) {
    const int midx = ((third - 1) * 256 + qg * 64 + lane) * 33;
#pragma unroll
    for (int r = 0; r < 16; ++r) { MG[midx + r] = acc0[r]; MG[midx + 16 + r] = acc1[r]; }
    MG[midx + 32] = ltot;
  }
  __syncthreads();
  if (third == 0) {
    const int m0 = (qg * 64 + lane) * 33;
    const int m1 = (256 + qg * 64 + lane) * 33;
#pragma unroll
    for (int r = 0; r < 16; ++r) {
      acc0[r] += MG[m0 + r] + MG[m1 + r];
      acc1[r] += MG[m0 + 16 + r] + MG[m1 + 16 + r];
    }
    ltot += MG[m0 + 32] + MG[m1 + 32];
    const float inv = 1.0f / ltot;
    const size_t orow0 = (size_t)(b * 2048 + qb * 128 + qg * 32);
#pragma unroll
    for (int r = 0; r < 16; ++r) {
      const int rowq = (r & 3) + 8 * (r >> 2) + 4 * hc;
      const float ir = __shfl(inv, rowq);
      out[(orow0 + rowq) * 1024 + h * 64 + l31]      = f2bf(acc0[r] * ir);
      out[(orow0 + rowq) * 1024 + h * 64 + 32 + l31] = f2bf(acc1[r] * ir);
    }
  }
}

// -------------------- launch --------------------
extern "C" void kernel_launch(void* const* d_in, const int* in_sizes, int n_in,
                              void* d_out, int out_size, void* d_ws, size_t ws_size,
                              hipStream_t stream) {
  const float* x      = (const float*)d_in[0];  // [2,2048,1024]
  const float* w_qkv  = (const float*)d_in[1];  // [3072,1024]
  const float* b_qkv  = (const float*)d_in[2];  // [3072]
  const float* w_proj = (const float*)d_in[3];  // [1024,1024]
  const float* b_proj = (const float*)d_in[4];  // [1024]
  float* out = (float*)d_out;                   // [2,2048,1024]

  char* ws = (char*)d_ws;
  u16* xb     = (u16*)(ws);                       // 8 MB   [4096,1024]
  u16* wqkvb  = (u16*)(ws + (8ull  << 20));       // 6 MB   [3072,1024]
  u16* wprojb = (u16*)(ws + (14ull << 20));       // 2 MB   [1024,1024]
  u16* qkvb   = (u16*)(ws + (16ull << 20));       // 24 MB  [4096,3072]
  u16* aob    = (u16*)(ws + (40ull << 20));       // 8 MB   [4096,1024]

  cvt_all<<<2048, 256, 0, stream>>>(x, w_qkv, w_proj, (ushort4*)ws);

  // qkv = x @ w_qkv^T + b_qkv -> bf16 [4096,3072]; q-cols pre-scaled by 0.125*log2e
  gemm256_bt<<<256, 512, 0, stream>>>(xb, wqkvb, b_qkv, qkvb, 4096, 3072, 1024);

  // fused attention -> bf16 [4096,1024] in [b,n,h,d] order (12 warps: 4qg x 3 KV-thirds)
  attn_fused<<<512, 768, 0, stream>>>(qkvb, aob);

  // y = attn_out @ w_proj^T + b_proj -> fp32 d_out
  gemm_bt<0><<<dim3(8, 32), 256, 0, stream>>>(aob, wprojb, b_proj, out, 4096, 1024, 1024);
}

// Round 10
// 106.427 us; speedup vs baseline: 3.2950x; 3.2950x over previous
//
#include <hip/hip_runtime.h>
#include <hip/hip_bf16.h>

typedef __attribute__((ext_vector_type(4))) float f32x4;
typedef __attribute__((ext_vector_type(16))) float f32x16;
typedef __attribute__((ext_vector_type(8))) short short8;
typedef __attribute__((ext_vector_type(4))) unsigned int u32x4;
typedef __attribute__((ext_vector_type(2))) unsigned int u32x2;
typedef unsigned short u16;

__device__ __forceinline__ u16 f2bf(float x) {
  unsigned u = __float_as_uint(x);
  u += 0x7fffu + ((u >> 16) & 1u);   // RNE
  return (u16)(u >> 16);
}

__device__ __forceinline__ void gload_lds16(const void* g, void* l) {
  __builtin_amdgcn_global_load_lds(
      (__attribute__((address_space(1))) void*)g,
      (__attribute__((address_space(3))) void*)l, 16, 0, 0);
}

// -------------------- fp32 -> bf16 convert (all 3 inputs, one kernel) -------------
__global__ void cvt_all(const float* __restrict__ x, const float* __restrict__ wq,
                        const float* __restrict__ wp, ushort4* __restrict__ dst) {
  const int N1 = 1048576, N2 = 786432, NT = 2097152;
  for (int i = blockIdx.x * 256 + threadIdx.x; i < NT; i += 524288) {
    float4 v;
    if (i < N1)            v = ((const float4*)x)[i];
    else if (i < N1 + N2)  v = ((const float4*)wq)[i - N1];
    else                   v = ((const float4*)wp)[i - N1 - N2];
    ushort4 o;
    o.x = f2bf(v.x); o.y = f2bf(v.y); o.z = f2bf(v.z); o.w = f2bf(v.w);
    dst[i] = o;
  }
}

// ==================== 256x192 GEMM (QKV): C = A B^T + bias, bf16 out ==============
// (unchanged from R8)
__global__ __launch_bounds__(512, 2) void gemm256_bt(
    const u16* __restrict__ A, const u16* __restrict__ B,
    const float* __restrict__ bias, u16* __restrict__ Cout,
    int M, int N, int K)
{
  __shared__ u16 LA[2][2][8192];
  __shared__ u16 LB[2][12288];

  const int tid  = threadIdx.x;
  const int w    = tid >> 6;
  const int lane = tid & 63;
  const int wm   = w >> 2;
  const int wn   = w & 3;
  const int hi   = lane >> 4;
  const int lo   = lane & 15;

  const int L  = (int)(blockIdx.x & 7) * 32 + (int)(blockIdx.x >> 3);
  const int bx = L >> 4, by = L & 15;
  const long brow = (long)by * 256;
  const long bcol = (long)bx * 192;

  f32x4 acc[8][3];
#pragma unroll
  for (int m = 0; m < 8; ++m)
#pragma unroll
    for (int n = 0; n < 3; ++n)
#pragma unroll
      for (int r = 0; r < 4; ++r) acc[m][n][r] = 0.0f;

  const int srow = lane >> 3;
  const int sg   = (lane & 7) ^ srow;
  const int l7   = lo & 7;

  auto stA = [&](int kt, int bi, int i) {
    const long k0 = (long)kt * 64;
#pragma unroll
    for (int mh = 0; mh < 2; ++mh) {
      const long r = brow + mh * 128 + i * 64 + w * 8 + srow;
      gload_lds16(A + r * K + k0 + sg * 8, &LA[bi][mh][i * 4096 + w * 512]);
    }
  };
  auto stB = [&](int kt, int bi, int u) {
    const long k0 = (long)kt * 64;
    const long r = bcol + u * 64 + w * 8 + srow;
    gload_lds16(B + r * K + k0 + sg * 8, &LB[bi][u * 4096 + w * 512]);
  };

  short8 a[4][2], b[3][2];
  auto rdA = [&](int bi, int mq) {
#pragma unroll
    for (int f = 0; f < 4; ++f) {
      const int rl = mq * 64 + f * 16 + lo;
#pragma unroll
      for (int ks = 0; ks < 2; ++ks)
        a[f][ks] = *(const short8*)(&LA[bi][wm][rl * 64 + ((ks * 4 + hi) ^ l7) * 8]);
    }
  };
  auto rdB = [&](int bi) {
#pragma unroll
    for (int f = 0; f < 3; ++f) {
      const int rl = wn * 48 + f * 16 + lo;
#pragma unroll
      for (int ks = 0; ks < 2; ++ks)
        b[f][ks] = *(const short8*)(&LB[bi][rl * 64 + ((ks * 4 + hi) ^ l7) * 8]);
    }
  };

#define MFMA24(mq)                                                                  \
  __builtin_amdgcn_s_setprio(1);                                                    \
  _Pragma("unroll")                                                                 \
  for (int f = 0; f < 4; ++f)                                                       \
    _Pragma("unroll")                                                               \
    for (int n = 0; n < 3; ++n)                                                     \
      _Pragma("unroll")                                                             \
      for (int ks = 0; ks < 2; ++ks)                                                \
        acc[(mq)*4 + f][n] = __builtin_amdgcn_mfma_f32_16x16x32_bf16(               \
            a[f][ks], b[n][ks], acc[(mq)*4 + f][n], 0, 0, 0);                       \
  __builtin_amdgcn_s_setprio(0);

#define PHASE_WAIT()                                      \
  __builtin_amdgcn_s_barrier();                           \
  asm volatile("s_waitcnt lgkmcnt(0)" ::: "memory");      \
  __builtin_amdgcn_sched_barrier(0);

  const int nkt = K >> 6;
  stA(0, 0, 0); stA(0, 0, 1); stB(0, 0, 0); stB(0, 0, 1); stB(0, 0, 2);
  stA(1, 1, 0); stA(1, 1, 1); stB(1, 1, 0); stB(1, 1, 1); stB(1, 1, 2);
  asm volatile("s_waitcnt vmcnt(7)" ::: "memory");
  __builtin_amdgcn_s_barrier();

  for (int it = 0; it < (nkt >> 1); ++it) {
    const int t2 = 2 * it + 2, t3 = 2 * it + 3;
    rdA(0, 0); rdB(0);
    if (it > 0) stA(2 * it + 1, 1, 1);
    PHASE_WAIT(); MFMA24(0); __builtin_amdgcn_s_barrier();
    rdA(0, 1);
    if (t2 < nkt) { stB(t2, 0, 0); stB(t2, 0, 1); stB(t2, 0, 2); stA(t2, 0, 0); }
    PHASE_WAIT(); MFMA24(1);
    if (t2 < nkt) { asm volatile("s_waitcnt vmcnt(5)" ::: "memory"); }
    else          { asm volatile("s_waitcnt vmcnt(0)" ::: "memory"); }
    __builtin_amdgcn_sched_barrier(0);
    __builtin_amdgcn_s_barrier();
    rdA(1, 0); rdB(1);
    if (t2 < nkt) stA(t2, 0, 1);
    PHASE_WAIT(); MFMA24(0); __builtin_amdgcn_s_barrier();
    rdA(1, 1);
    if (t3 < nkt) { stB(t3, 1, 0); stB(t3, 1, 1); stB(t3, 1, 2); stA(t3, 1, 0); }
    PHASE_WAIT(); MFMA24(1);
    if (t3 < nkt) { asm volatile("s_waitcnt vmcnt(5)" ::: "memory"); }
    __builtin_amdgcn_sched_barrier(0);
    __builtin_amdgcn_s_barrier();
  }
#undef MFMA24
#undef PHASE_WAIT

  const float SCC = 0.18033688011112042f;
  float bv[3];
#pragma unroll
  for (int n = 0; n < 3; ++n) bv[n] = bias[bcol + wn * 48 + n * 16 + lo];
#pragma unroll
  for (int m = 0; m < 8; ++m)
#pragma unroll
    for (int n = 0; n < 3; ++n) {
      const long colf = bcol + wn * 48 + n * 16;
      const float qsc = (colf < 1024) ? SCC : 1.0f;
#pragma unroll
      for (int r = 0; r < 4; ++r) {
        const long row = brow + wm * 128 + m * 16 + hi * 4 + r;
        Cout[row * (long)N + colf + lo] = f2bf((acc[m][n][r] + bv[n]) * qsc);
      }
    }
}

// -------------------- GEMM: C[M,N] = A[M,K] * B[N,K]^T + bias (128^2, 2-phase) ----
template<int OUT_BF16>
__global__ __launch_bounds__(256) void gemm_bt(
    const u16* __restrict__ A, const u16* __restrict__ B,
    const float* __restrict__ bias, void* __restrict__ Cout,
    int M, int N, int K)
{
  __shared__ u16 As[2][128 * 64];
  __shared__ u16 Bs[2][128 * 64];
  const int tid  = threadIdx.x;
  const int lane = tid & 63;
  const int w    = tid >> 6;
  const int wm   = w >> 1, wn = w & 1;
  const int hi   = lane >> 4;
  const int lo   = lane & 15;
  const int l7   = lo & 7;
  const long brow = (long)blockIdx.y * 128;
  const long bcol = (long)blockIdx.x * 128;

  f32x4 acc[4][4];
#pragma unroll
  for (int i = 0; i < 4; i++)
#pragma unroll
    for (int j = 0; j < 4; j++)
#pragma unroll
      for (int r = 0; r < 4; r++) acc[i][j][r] = 0.0f;

  const int srow = lane >> 3;
  const int sg   = (lane & 7) ^ srow;

  float bv[4];
#pragma unroll
  for (int fn = 0; fn < 4; fn++) bv[fn] = bias[bcol + wn * 64 + fn * 16 + lo];

  auto stage = [&](int kt, int bi) {
    const int k0 = kt << 6;
#pragma unroll
    for (int c = 0; c < 4; ++c) {
      const int chunk = (c << 2) + w;
      const int ra = (chunk << 3) + srow;
      gload_lds16(A + (size_t)(brow + ra) * K + k0 + sg * 8, &As[bi][chunk * 512]);
      gload_lds16(B + (size_t)(bcol + ra) * K + k0 + sg * 8, &Bs[bi][chunk * 512]);
    }
  };

  const int nkt = K >> 6;
  stage(0, 0);
  __syncthreads();
  int cur = 0;

  for (int kt = 0; kt < nkt; ++kt) {
    if (kt + 1 < nkt) stage(kt + 1, cur ^ 1);
#pragma unroll
    for (int ks = 0; ks < 2; ++ks) {
      short8 af[4], bfr[4];
      const int g = ((ks * 4 + hi) ^ l7) * 8;
#pragma unroll
      for (int f = 0; f < 4; f++) {
        af[f]  = *(const short8*)(&As[cur][(wm * 64 + f * 16 + lo) * 64 + g]);
        bfr[f] = *(const short8*)(&Bs[cur][(wn * 64 + f * 16 + lo) * 64 + g]);
      }
#pragma unroll
      for (int fm = 0; fm < 4; fm++)
#pragma unroll
        for (int fn = 0; fn < 4; fn++)
          acc[fm][fn] = __builtin_amdgcn_mfma_f32_16x16x32_bf16(af[fm], bfr[fn], acc[fm][fn], 0, 0, 0);
    }
    __syncthreads();
    cur ^= 1;
  }

#pragma unroll
  for (int fm = 0; fm < 4; fm++)
#pragma unroll
    for (int fn = 0; fn < 4; fn++)
#pragma unroll
      for (int r = 0; r < 4; r++) {
        const long row = brow + wm * 64 + fm * 16 + hi * 4 + r;
        const long col = bcol + wn * 64 + fn * 16 + lo;
        const float v = acc[fm][fn][r] + bv[fn];
        if (OUT_BF16) ((u16*)Cout)[row * (long)N + col] = f2bf(v);
        else          ((float*)Cout)[row * (long)N + col] = v;
      }
}

// -------------------- fused flash attention ----------------------------------------
// 8 warps = 4 q-subgroups (32 rows) x 2 KV-halves (1024 keys each).
// V SINGLE-buffered (R9's verified-correct schedule, at R8's register footprint):
// per tile {stK(t+1) | QK(t) | softmax | vmcnt(2|0)+bar | PV(t) | vmcnt(0)+bar | stV(t+1)}
// LDS 48 KB (K dbuf 32K + V 16K) -> 3 blocks/CU = 24 waves/CU at VGPR~60 (no
// launch_bounds squeeze: occupancy earned by actual use, not declared — R9 lesson).
__global__ __launch_bounds__(512, 4) void attn_fused(
    const u16* __restrict__ qkv, u16* __restrict__ out)
{
  __shared__ __align__(16) char smem[49152];

  const int tid  = threadIdx.x;
  const int w    = tid >> 6;
  const int lane = tid & 63;
  const int l31  = lane & 31;
  const int hc   = lane >> 5;        // wave half
  const int g1   = (lane >> 4) & 1;  // d16 select for tr-read
  const int l15  = lane & 15;
  const int half = w >> 2;           // KV half
  const int qg   = w & 3;            // q subgroup (32 rows)

  const int bid  = blockIdx.x;
  const int xcd  = bid & 7;
  const int slot = bid >> 3;
  const int qb   = slot & 15;
  const int bh   = ((slot >> 4) << 3) | xcd;
  const int b    = bh >> 4, h = bh & 15;

  short8 qf[4];
  {
    const u16* qp = qkv + (size_t)(b * 2048 + qb * 128 + qg * 32 + l31) * 3072 + h * 64 + hc * 8;
#pragma unroll
    for (int ds = 0; ds < 4; ++ds) qf[ds] = *(const short8*)(qp + ds * 16);
  }

  f32x16 acc0, acc1;
#pragma unroll
  for (int r = 0; r < 16; ++r) { acc0[r] = 0.f; acc1[r] = 0.f; }
  float lsum = 0.f;

  const int srow8 = lane >> 3;
  const int kgl   = (lane & 7) ^ srow8;
  const int vkey  = (lane >> 5) * 4 + ((lane >> 1) & 3);
  const int vd    = ((lane >> 3) & 3) * 16 + (lane & 1) * 8;

  auto kbuf = [&](int bi) { return (u16*)(smem + (size_t)(half * 2 + bi) * 8192); };
  u16* vb = (u16*)(smem + 32768 + (size_t)half * 8192);

  auto stK = [&](int t, int bi) {
    const size_t rbase = (size_t)(b * 2048 + half * 1024 + t * 64);
    u16* Kb = kbuf(bi);
#pragma unroll
    for (int c = 0; c < 2; ++c) {
      const int chunk = qg * 2 + c;
      gload_lds16(qkv + (rbase + chunk * 8 + srow8) * 3072 + 1024 + h * 64 + kgl * 8,
                  Kb + chunk * 512);
    }
  };
  auto stV = [&](int t) {
    const size_t rbase = (size_t)(b * 2048 + half * 1024 + t * 64);
#pragma unroll
    for (int c = 0; c < 2; ++c) {
      const int chunk = qg * 2 + c;
      gload_lds16(qkv + (rbase + chunk * 8 + vkey) * 3072 + 2048 + h * 64 + vd,
                  vb + chunk * 512);
    }
  };

  // prologue
  stK(0, 0); stV(0);
  asm volatile("s_waitcnt vmcnt(0)" ::: "memory");
  __builtin_amdgcn_s_barrier();
  int cur = 0;

  for (int t = 0; t < 16; ++t) {
    const bool pfK = t < 15;
    if (pfK) stK(t + 1, cur ^ 1);

    const u16* Kc = kbuf(cur);

    f32x16 s0, s1;
#pragma unroll
    for (int r = 0; r < 16; ++r) { s0[r] = 0.f; s1[r] = 0.f; }
    __builtin_amdgcn_s_setprio(1);
#pragma unroll
    for (int ds = 0; ds < 4; ++ds) {
      const int gb = (((2 * ds + hc) ^ (lane & 7)) << 4);
      const short8 k0 = *(const short8*)((const char*)Kc + l31 * 128 + gb);
      const short8 k1 = *(const short8*)((const char*)Kc + 4096 + l31 * 128 + gb);
      s0 = __builtin_amdgcn_mfma_f32_32x32x16_bf16(k0, qf[ds], s0, 0, 0, 0);
      s1 = __builtin_amdgcn_mfma_f32_32x32x16_bf16(k1, qf[ds], s1, 0, 0, 0);
    }
    __builtin_amdgcn_s_setprio(0);

    // ---- P = exp2(S) (Q pre-scaled; shift-free), accumulate row-sum
    float p[32];
#pragma unroll
    for (int r = 0; r < 16; ++r) {
      p[r]      = __builtin_amdgcn_exp2f(s0[r]);
      p[16 + r] = __builtin_amdgcn_exp2f(s1[r]);
    }
    {
      float a0 = 0.f, a1 = 0.f, a2 = 0.f, a3 = 0.f;
#pragma unroll
      for (int r = 0; r < 8; ++r) {
        a0 += p[r]; a1 += p[8 + r]; a2 += p[16 + r]; a3 += p[24 + r];
      }
      lsum += (a0 + a1) + (a2 + a3);
    }

    // ---- PA-frags: cvt_pk pairs + permlane32_swap
    short8 pa[4];
#pragma unroll
    for (int ks = 0; ks < 4; ++ks) {
      const int bs = ks * 8;
      unsigned X0, X1, X2, X3;
      asm("v_cvt_pk_bf16_f32 %0, %1, %2" : "=v"(X0) : "v"(p[bs + 0]), "v"(p[bs + 1]));
      asm("v_cvt_pk_bf16_f32 %0, %1, %2" : "=v"(X1) : "v"(p[bs + 2]), "v"(p[bs + 3]));
      asm("v_cvt_pk_bf16_f32 %0, %1, %2" : "=v"(X2) : "v"(p[bs + 4]), "v"(p[bs + 5]));
      asm("v_cvt_pk_bf16_f32 %0, %1, %2" : "=v"(X3) : "v"(p[bs + 6]), "v"(p[bs + 7]));
      asm("v_permlane32_swap_b32 %0, %1" : "+v"(X0), "+v"(X2));
      asm("v_permlane32_swap_b32 %0, %1" : "+v"(X1), "+v"(X3));
      u32x4 wv;
      wv[0] = X0; wv[1] = X1; wv[2] = X2; wv[3] = X3;
      pa[ks] = __builtin_bit_cast(short8, wv);
    }

    // mid gate: own V-writes drained (K(t+1)'s 2 loads may stay in flight);
    // barrier makes all warps' V writes visible before PV reads
    if (pfK) { asm volatile("s_waitcnt vmcnt(2)" ::: "memory"); }
    else     { asm volatile("s_waitcnt vmcnt(0)" ::: "memory"); }
    __builtin_amdgcn_sched_barrier(0);
    __builtin_amdgcn_s_barrier();

    // ---- O += P · V
    {
      const unsigned va =
          (unsigned)(unsigned long long)(const __attribute__((address_space(3))) u16*)vb;
#pragma unroll
      for (int dt = 0; dt < 2; ++dt) {
        const unsigned vba = va + (unsigned)(hc * 1024 + dt * 256 + g1 * 128 + l15 * 8);
        u32x2 q0, q1, q2, q3, q4, q5, q6, q7;
        asm volatile("ds_read_b64_tr_b16 %0, %1"             : "=v"(q0) : "v"(vba));
        asm volatile("ds_read_b64_tr_b16 %0, %1 offset:512"  : "=v"(q1) : "v"(vba));
        asm volatile("ds_read_b64_tr_b16 %0, %1 offset:2048" : "=v"(q2) : "v"(vba));
        asm volatile("ds_read_b64_tr_b16 %0, %1 offset:2560" : "=v"(q3) : "v"(vba));
        asm volatile("ds_read_b64_tr_b16 %0, %1 offset:4096" : "=v"(q4) : "v"(vba));
        asm volatile("ds_read_b64_tr_b16 %0, %1 offset:4608" : "=v"(q5) : "v"(vba));
        asm volatile("ds_read_b64_tr_b16 %0, %1 offset:6144" : "=v"(q6) : "v"(vba));
        asm volatile("ds_read_b64_tr_b16 %0, %1 offset:6656" : "=v"(q7) : "v"(vba));
        asm volatile("s_waitcnt lgkmcnt(0)" ::: "memory");
        __builtin_amdgcn_sched_barrier(0);
        __builtin_amdgcn_s_setprio(1);
        f32x16 A = dt ? acc1 : acc0;
        {
          u32x4 bb; bb[0] = q0[0]; bb[1] = q0[1]; bb[2] = q1[0]; bb[3] = q1[1];
          A = __builtin_amdgcn_mfma_f32_32x32x16_bf16(pa[0], __builtin_bit_cast(short8, bb), A, 0, 0, 0);
        }
        {
          u32x4 bb; bb[0] = q2[0]; bb[1] = q2[1]; bb[2] = q3[0]; bb[3] = q3[1];
          A = __builtin_amdgcn_mfma_f32_32x32x16_bf16(pa[1], __builtin_bit_cast(short8, bb), A, 0, 0, 0);
        }
        {
          u32x4 bb; bb[0] = q4[0]; bb[1] = q4[1]; bb[2] = q5[0]; bb[3] = q5[1];
          A = __builtin_amdgcn_mfma_f32_32x32x16_bf16(pa[2], __builtin_bit_cast(short8, bb), A, 0, 0, 0);
        }
        {
          u32x4 bb; bb[0] = q6[0]; bb[1] = q6[1]; bb[2] = q7[0]; bb[3] = q7[1];
          A = __builtin_amdgcn_mfma_f32_32x32x16_bf16(pa[3], __builtin_bit_cast(short8, bb), A, 0, 0, 0);
        }
        __builtin_amdgcn_s_setprio(0);
        if (dt) acc1 = A; else acc0 = A;
      }
    }

    // end gate: K(t+1) drained; all PV reads of vb done across warps -> V(t+1) may land
    asm volatile("s_waitcnt vmcnt(0)" ::: "memory");
    __builtin_amdgcn_sched_barrier(0);
    __builtin_amdgcn_s_barrier();

    if (pfK) stV(t + 1);
    cur ^= 1;
  }

  // ---- merge KV-halves via LDS (shift-free softmax => purely additive) ----
  float ltot = lsum + __shfl_xor(lsum, 32);
  float* MG = (float*)smem;
  const int midx = (qg * 64 + lane) * 33;
  if (half == 1) {
#pragma unroll
    for (int r = 0; r < 16; ++r) { MG[midx + r] = acc0[r]; MG[midx + 16 + r] = acc1[r]; }
    MG[midx + 32] = ltot;
  }
  __syncthreads();
  if (half == 0) {
#pragma unroll
    for (int r = 0; r < 16; ++r) { acc0[r] += MG[midx + r]; acc1[r] += MG[midx + 16 + r]; }
    ltot += MG[midx + 32];
    const float inv = 1.0f / ltot;
    const size_t orow0 = (size_t)(b * 2048 + qb * 128 + qg * 32);
#pragma unroll
    for (int r = 0; r < 16; ++r) {
      const int rowq = (r & 3) + 8 * (r >> 2) + 4 * hc;
      const float ir = __shfl(inv, rowq);
      out[(orow0 + rowq) * 1024 + h * 64 + l31]      = f2bf(acc0[r] * ir);
      out[(orow0 + rowq) * 1024 + h * 64 + 32 + l31] = f2bf(acc1[r] * ir);
    }
  }
}

// -------------------- launch --------------------
extern "C" void kernel_launch(void* const* d_in, const int* in_sizes, int n_in,
                              void* d_out, int out_size, void* d_ws, size_t ws_size,
                              hipStream_t stream) {
  const float* x      = (const float*)d_in[0];  // [2,2048,1024]
  const float* w_qkv  = (const float*)d_in[1];  // [3072,1024]
  const float* b_qkv  = (const float*)d_in[2];  // [3072]
  const float* w_proj = (const float*)d_in[3];  // [1024,1024]
  const float* b_proj = (const float*)d_in[4];  // [1024]
  float* out = (float*)d_out;                   // [2,2048,1024]

  char* ws = (char*)d_ws;
  u16* xb     = (u16*)(ws);                       // 8 MB   [4096,1024]
  u16* wqkvb  = (u16*)(ws + (8ull  << 20));       // 6 MB   [3072,1024]
  u16* wprojb = (u16*)(ws + (14ull << 20));       // 2 MB   [1024,1024]
  u16* qkvb   = (u16*)(ws + (16ull << 20));       // 24 MB  [4096,3072]
  u16* aob    = (u16*)(ws + (40ull << 20));       // 8 MB   [4096,1024]

  cvt_all<<<2048, 256, 0, stream>>>(x, w_qkv, w_proj, (ushort4*)ws);

  // qkv = x @ w_qkv^T + b_qkv -> bf16 [4096,3072]; q-cols pre-scaled by 0.125*log2e
  gemm256_bt<<<256, 512, 0, stream>>>(xb, wqkvb, b_qkv, qkvb, 4096, 3072, 1024);

  // fused attention -> bf16 [4096,1024] in [b,n,h,d] order
  attn_fused<<<512, 512, 0, stream>>>(qkvb, aob);

  // y = attn_out @ w_proj^T + b_proj -> fp32 d_out
  gemm_bt<0><<<dim3(8, 32), 256, 0, stream>>>(aob, wprojb, b_proj, out, 4096, 1024, 1024);
}